// Round 10
// baseline (26861.200 us; speedup 1.0000x reference)
//
#include <hip/hip_runtime.h>
#include <math.h>

#define EPSN 1e-5f
#define BATCH 8
#define NCH 64
#define XROW 8192
#define L0IN 8128
#define L1P1 4058
#define LOUTP1 3968
#define WLEN 194
#define NSTEP 32
#define OUTROW 4000

__device__ __forceinline__ float gelu_f(float x){
    float x3 = x*x*x;
    return 0.5f*x*(1.0f + tanhf(0.7978845608028654f*(x + 0.044715f*x3)));
}

__device__ __forceinline__ float bn_gelu(float v, float sum, float sumsq, float invN, float s, float b){
    float m = sum*invN;
    float var = sumsq*invN - m*m;
    float rs = rsqrtf(var + EPSN);
    return gelu_f((v - m)*rs*s + b);
}

// ---------------- scalar stats (1-channel input), single block ----------------
__global__ void k_stats_scalar(const float* __restrict__ in, int bstride, int T, float* __restrict__ st){
    __shared__ float red[2048];
    int tid = threadIdx.x;
    float s = 0.f, sq = 0.f;
    int N = BATCH*T;
    for (int idx = tid; idx < N; idx += 1024){
        int b = idx / T, t = idx % T;
        float v = in[b*bstride + t];
        s += v; sq += v*v;
    }
    red[tid] = s; red[1024+tid] = sq;
    __syncthreads();
    for (int w = 512; w > 0; w >>= 1){
        if (tid < w){ red[tid] += red[tid+w]; red[1024+tid] += red[1024+tid+w]; }
        __syncthreads();
    }
    if (tid == 0){ st[0] = red[0]; st[1] = red[1024]; }
}

// ---------------- conv k=14 stride=2, 1ch input with analytic layer_in bn+gelu ----------------
__global__ void k_conv0(const float* __restrict__ in, int bstride, int Lin, int Lout,
                        const float* __restrict__ stX,
                        const float* __restrict__ w_in, const float* __restrict__ s_in, const float* __restrict__ b_in,
                        const float* __restrict__ w0,
                        float* __restrict__ out, float* __restrict__ stOut){
    __shared__ float lds[64*45];
    __shared__ float red[512];
    int b = blockIdx.y;
    int t0 = blockIdx.x * 16;
    int tid = threadIdx.x;
    int co = tid & 63, tg = tid >> 6;
    float invNx = 1.0f/(float)(BATCH*Lin);
    float mx = stX[0]*invNx;
    float vx = stX[1]*invNx - mx*mx;
    for (int idx = tid; idx < 44*64; idx += 256){
        int p = idx >> 6; int ci = idx & 63;
        int gp = 2*t0 + p;
        float val = 0.f;
        if (gp < Lin){
            float wc = w_in[ci];
            float raw = in[b*bstride + gp] * wc;
            float var = vx*wc*wc;
            float rs = rsqrtf(var + EPSN);
            val = gelu_f((raw - mx*wc)*rs*s_in[ci] + b_in[ci]);
        }
        lds[ci*45 + p] = val;
    }
    __syncthreads();
    float acc[4] = {0.f,0.f,0.f,0.f};
    for (int ci = 0; ci < 64; ++ci){
        float r[20];
        #pragma unroll
        for (int q = 0; q < 20; ++q) r[q] = lds[ci*45 + 8*tg + q];
        #pragma unroll
        for (int k = 0; k < 14; ++k){
            float w = w0[(k*64+ci)*64 + co];
            #pragma unroll
            for (int j = 0; j < 4; ++j) acc[j] = fmaf(r[2*j+k], w, acc[j]);
        }
    }
    float s = 0.f, sq = 0.f;
    #pragma unroll
    for (int j = 0; j < 4; ++j){
        int t = t0 + tg*4 + j;
        if (t < Lout){
            out[(b*Lout + t)*64 + co] = acc[j];
            s += acc[j]; sq += acc[j]*acc[j];
        }
    }
    red[tid] = s; red[256+tid] = sq;
    __syncthreads();
    if (tg == 0){
        float S  = red[co] + red[co+64] + red[co+128] + red[co+192];
        float SQ = red[256+co] + red[256+co+64] + red[256+co+128] + red[256+co+192];
        atomicAdd(&stOut[2*co],   S);
        atomicAdd(&stOut[2*co+1], SQ);
    }
}

// ---------------- conv k=7 stride=1, input = g(P) applied in LDS stage ----------------
__global__ void k_conv7(const float* __restrict__ P, int LP,
                        const float* __restrict__ stP, const float* __restrict__ s2, const float* __restrict__ b2,
                        const float* __restrict__ w,
                        float* __restrict__ Q, int LQ, float* __restrict__ stQ){
    __shared__ float lds[64*23];
    __shared__ float red[512];
    int b = blockIdx.y;
    int t0 = blockIdx.x * 16;
    int tid = threadIdx.x;
    int co = tid & 63, tg = tid >> 6;
    float invNp = 1.0f/(float)(BATCH*LP);
    for (int idx = tid; idx < 22*64; idx += 256){
        int p = idx >> 6; int ci = idx & 63;
        int gt = t0 + p;
        float val = 0.f;
        if (gt < LP){
            float raw = P[(b*LP + gt)*64 + ci];
            val = bn_gelu(raw, stP[2*ci], stP[2*ci+1], invNp, s2[ci], b2[ci]);
        }
        lds[ci*23 + p] = val;
    }
    __syncthreads();
    float acc[4] = {0.f,0.f,0.f,0.f};
    for (int ci = 0; ci < 64; ++ci){
        float r[10];
        #pragma unroll
        for (int q = 0; q < 10; ++q) r[q] = lds[ci*23 + tg*4 + q];
        #pragma unroll
        for (int k = 0; k < 7; ++k){
            float wv = w[(k*64+ci)*64 + co];
            #pragma unroll
            for (int j = 0; j < 4; ++j) acc[j] = fmaf(r[j+k], wv, acc[j]);
        }
    }
    float s = 0.f, sq = 0.f;
    #pragma unroll
    for (int j = 0; j < 4; ++j){
        int t = t0 + tg*4 + j;
        if (t < LQ){
            Q[(b*LQ + t)*64 + co] = acc[j];
            s += acc[j]; sq += acc[j]*acc[j];
        }
    }
    red[tid] = s; red[256+tid] = sq;
    __syncthreads();
    if (tg == 0){
        float S  = red[co] + red[co+64] + red[co+128] + red[co+192];
        float SQ = red[256+co] + red[256+co+64] + red[256+co+128] + red[256+co+192];
        atomicAdd(&stQ[2*co],   S);
        atomicAdd(&stQ[2*co+1], SQ);
    }
}

// ---------------- elementwise: Q = gelu(bn1(Q_raw)) [+ g(P[t+6])*wsk], stats of result ----------------
__global__ void k_elem(float* __restrict__ Q, int LQ,
                       const float* __restrict__ stQ, const float* __restrict__ s1, const float* __restrict__ b1,
                       const float* __restrict__ P, int LP,
                       const float* __restrict__ stP, const float* __restrict__ s2, const float* __restrict__ b2,
                       const float* __restrict__ wsk,
                       float* __restrict__ stOut){
    __shared__ float red[512];
    int tid = threadIdx.x;
    int c = tid & 63;
    int N = BATCH*LQ*64;
    int stride = gridDim.x*blockDim.x;
    float invNq = 1.0f/(float)(BATCH*LQ);
    float invNp = P ? 1.0f/(float)(BATCH*LP) : 0.f;
    float s = 0.f, sq = 0.f;
    for (int idx = blockIdx.x*blockDim.x + tid; idx < N; idx += stride){
        float v = Q[idx];
        float y = bn_gelu(v, stQ[2*c], stQ[2*c+1], invNq, s1[c], b1[c]);
        if (P){
            int bt = idx >> 6;
            int t  = bt % LQ;
            int bb = bt / LQ;
            float pv = P[(bb*LP + t + 6)*64 + c];
            y += bn_gelu(pv, stP[2*c], stP[2*c+1], invNp, s2[c], b2[c]) * wsk[c];
        }
        Q[idx] = y;
        s += y; sq += y*y;
    }
    red[tid] = s; red[256+tid] = sq;
    __syncthreads();
    if (tid < 64){
        float S  = red[c] + red[c+64] + red[c+128] + red[c+192];
        float SQ = red[256+c] + red[256+c+64] + red[256+c+128] + red[256+c+192];
        atomicAdd(&stOut[2*c],   S);
        atomicAdd(&stOut[2*c+1], SQ);
    }
}

// ---------------- output conv (64->1) with scalar stats ----------------
__global__ void k_convout(const float* __restrict__ P, int LQ,
                          const float* __restrict__ stP, const float* __restrict__ s2, const float* __restrict__ b2,
                          const float* __restrict__ w_out,
                          float* __restrict__ o_raw, float* __restrict__ stOut){
    __shared__ float red[8];
    int tid = threadIdx.x;
    int c = tid & 63, tq = tid >> 6;
    int M = BATCH*LQ;
    float invNp = 1.0f/(float)(BATCH*LQ);
    float myw = w_out[c];
    float ms = stP[2*c], msq = stP[2*c+1], ss = s2[c], bb = b2[c];
    float ls = 0.f, lq = 0.f;
    for (int m = blockIdx.x*4 + tq; m < M; m += gridDim.x*4){
        float pv = P[m*64 + c];
        float val = bn_gelu(pv, ms, msq, invNp, ss, bb) * myw;
        #pragma unroll
        for (int off = 32; off > 0; off >>= 1) val += __shfl_down(val, off, 64);
        if (c == 0){ o_raw[m] = val; ls += val; lq += val*val; }
    }
    if (c == 0){ red[tq] = ls; red[4+tq] = lq; }
    __syncthreads();
    if (tid == 0){
        atomicAdd(&stOut[0], red[0]+red[1]+red[2]+red[3]);
        atomicAdd(&stOut[1], red[4]+red[5]+red[6]+red[7]);
    }
}

// ---------------- phase-1 finalize: z0 -> d_out ----------------
__global__ void k_finalize1(const float* __restrict__ o_raw, const float* __restrict__ st,
                            const float* __restrict__ s_out, const float* __restrict__ b_out,
                            float* __restrict__ out){
    float invN = 1.0f/(float)(BATCH*LOUTP1);
    float m = st[0]*invN;
    float var = st[1]*invN - m*m;
    float rs = rsqrtf(var + EPSN);
    float so = s_out[0], bo = b_out[0];
    int N = BATCH*LOUTP1;
    for (int idx = blockIdx.x*blockDim.x + threadIdx.x; idx < N; idx += gridDim.x*blockDim.x){
        int b = idx / LOUTP1, t = idx % LOUTP1;
        out[b*OUTROW + t] = (o_raw[idx]-m)*rs*so + bo;
    }
}

// ---------------- init rolling window + stats ----------------
__global__ void k_initW(const float* __restrict__ x, const float* __restrict__ out,
                        float* __restrict__ W, float* __restrict__ stX){
    __shared__ float red[512];
    int tid = threadIdx.x;
    float s = 0.f, sq = 0.f;
    for (int idx = tid; idx < BATCH*WLEN; idx += 256){
        int b = idx / WLEN, j = idx % WLEN;
        float v;
        if (j < 192)       v = x[b*XROW + 7936 + j];
        else if (j == 192) v = x[b*XROW + 8128];
        else               v = out[b*OUTROW + 3967];
        W[b*WLEN + j] = v;
        s += v; sq += v*v;
    }
    red[tid] = s; red[256+tid] = sq;
    __syncthreads();
    for (int w = 128; w > 0; w >>= 1){
        if (tid < w){ red[tid] += red[tid+w]; red[256+tid] += red[256+tid+w]; }
        __syncthreads();
    }
    if (tid == 0){ stX[0] = red[0]; stX[1] = red[256]; }
}

// ---------------- weight transpose for phase 2: [k][ci/4][co][ci%4] ----------------
// Per-lane float4 weight loads become coalesced (lane=co, 16B/lane contiguous).
__global__ void k_wtrans(const float* __restrict__ w0, const float* __restrict__ wconv,
                         float* __restrict__ w0t, float* __restrict__ wct){
    int tid = blockIdx.x*256 + threadIdx.x;
    int gs  = gridDim.x*256;
    for (int o = tid; o < 14*16*256; o += gs){
        int cilo = o & 3, co = (o>>2)&63, cihi = (o>>8)&15, kk = o>>12;
        w0t[o] = w0[(kk*64 + cihi*4+cilo)*64 + co];
    }
    for (int o = tid; o < 15*7*16*256; o += gs){
        int cilo = o & 3, co = (o>>2)&63, cihi = (o>>8)&15, r = o>>12;
        int kk = r % 7, i = r / 7;
        wct[o] = wconv[((i*7+kk)*64 + cihi*4+cilo)*64 + co];
    }
}

// ================= PHASE 2: 8 WGs (one per b), tensors LDS-resident =================
#define G2 8
#define NTH2 1024
#define BST 100  // float4-aligned; reads are wave-uniform broadcasts; rw passes 2-way-free

// All cross-WG traffic via atomic RMW at the coherence point (rounds 5-8: acquire-polls
// thrash L2; relaxed-load polls can spin on stale per-XCD L2 lines).
__device__ __forceinline__ float ld_rmw(float* p){
    return __hip_atomic_fetch_add(p, 0.0f, __ATOMIC_RELAXED, __HIP_MEMORY_SCOPE_AGENT);
}
__device__ __forceinline__ void st_rmw(float* p, float v){
    (void)__hip_atomic_exchange(p, v, __ATOMIC_RELAXED, __HIP_MEMORY_SCOPE_AGENT);
}

struct P2A {
    const float* x;
    float* out;
    const float* W;
    const float* stx;
    float* par;        // 34 slots * 1024 floats, overwrite-before-read
    int*   bar;
    const float* w_in; const float* s_in; const float* b_in;
    const float* w0t;  // 14*16*256 transposed
    const float* wct;  // 15*7*16*256 transposed
    const float* wskip; const float* wout;
    const float* s0a; const float* b0a; const float* s0b; const float* b0b;
    const float* sa; const float* ba; const float* sb; const float* bbv;
    const float* s_out; const float* b_out;
};

__device__ __forceinline__ void gsync(int* bar, int* phase){
    (*phase)++;
    int target = G2 * (*phase);
    asm volatile("s_waitcnt vmcnt(0)" ::: "memory");
    __syncthreads();
    if (threadIdx.x == 0){
        __hip_atomic_fetch_add(bar, 1, __ATOMIC_RELAXED, __HIP_MEMORY_SCOPE_AGENT);
        while (__hip_atomic_fetch_add(bar, 0, __ATOMIC_RELAXED, __HIP_MEMORY_SCOPE_AGENT) < target){
            __builtin_amdgcn_s_sleep(1);
        }
    }
    __syncthreads();
    asm volatile("" ::: "memory");
}

__global__ __launch_bounds__(NTH2) void k_phase2(P2A a){
    __shared__ float g0[64*208];
    __shared__ float bufs[2][64*BST + 16];   // +16 pad: b128 reads may overrun row 63 by <=4
    __shared__ float red[2048];
    __shared__ float sst[128];
    __shared__ float Wl[208];
    __shared__ float shv[16];
    __shared__ float stxl[2];

    const int tid  = threadIdx.x;
    const int wg   = blockIdx.x;
    const int lane = tid & 63;
    const int w    = tid >> 6;
    int phase = 0;

    if (tid < 194)            Wl[tid] = a.W[wg*WLEN + tid];
    else if (tid < 208)       Wl[tid] = 0.f;
    if (tid < 2)              stxl[tid] = a.stx[tid];
    __syncthreads();

    for (int k = 0; k < NSTEP; ++k){
        // ========== stage 0: conv0 (k=14, stride 2) ==========
        {
            const float invNx = 1.0f/(8.0f*194.0f);
            float mx = stxl[0]*invNx;
            float vx = stxl[1]*invNx - mx*mx;
            #pragma unroll
            for (int m = 0; m < 4; ++m){
                int ci = w + 16*m;
                float wc = a.w_in[ci];
                float rs = rsqrtf(vx*wc*wc + EPSN);
                float al = wc*rs*a.s_in[ci];
                float be = a.b_in[ci] - mx*al;
                for (int p = lane; p < 208; p += 64)
                    g0[ci*208 + p] = (p < 194) ? gelu_f(al*Wl[p] + be) : 0.f;
            }
            __syncthreads();
            float acc[8] = {0.f,0.f,0.f,0.f,0.f,0.f,0.f,0.f};
            int t0 = 8*w;
            if (w < 12){
                const float4* W0t4 = (const float4*)a.w0t;
                for (int cihi = 0; cihi < 16; ++cihi){
                    float r[4][28];
                    #pragma unroll
                    for (int cl = 0; cl < 4; ++cl){
                        const float4* ap = (const float4*)&g0[(cihi*4+cl)*208 + 2*t0];
                        #pragma unroll
                        for (int qq = 0; qq < 7; ++qq){
                            float4 v = ap[qq];
                            r[cl][qq*4+0]=v.x; r[cl][qq*4+1]=v.y; r[cl][qq*4+2]=v.z; r[cl][qq*4+3]=v.w;
                        }
                    }
                    #pragma unroll
                    for (int kk = 0; kk < 14; ++kk){
                        float4 wq = W0t4[(kk*16+cihi)*64 + lane];
                        #pragma unroll
                        for (int j = 0; j < 8; ++j){
                            acc[j] = fmaf(r[0][2*j+kk], wq.x, acc[j]);
                            acc[j] = fmaf(r[1][2*j+kk], wq.y, acc[j]);
                            acc[j] = fmaf(r[2][2*j+kk], wq.z, acc[j]);
                            acc[j] = fmaf(r[3][2*j+kk], wq.w, acc[j]);
                        }
                    }
                }
            }
            float s = 0.f, sq = 0.f;
            if (w < 12){
                if (t0 + 8 <= 91){
                    *(float4*)&bufs[0][lane*BST + t0]     = make_float4(acc[0],acc[1],acc[2],acc[3]);
                    *(float4*)&bufs[0][lane*BST + t0 + 4] = make_float4(acc[4],acc[5],acc[6],acc[7]);
                    #pragma unroll
                    for (int j = 0; j < 8; ++j){ s += acc[j]; sq += acc[j]*acc[j]; }
                } else {
                    #pragma unroll
                    for (int j = 0; j < 8; ++j){
                        int t = t0 + j;
                        if (t < 91){ bufs[0][lane*BST + t] = acc[j]; s += acc[j]; sq += acc[j]*acc[j]; }
                    }
                }
            }
            red[w*128 + 2*lane] = s; red[w*128 + 2*lane + 1] = sq;
            __syncthreads();
            if (tid < 128){
                float p = 0.f;
                #pragma unroll
                for (int q = 0; q < 16; ++q) p += red[q*128 + tid];
                st_rmw(&a.par[0*1024 + wg*128 + tid], p);
            }
        }
        gsync(a.bar, &phase);
        // ========== stage 1: elem0 ==========
        {
            if (tid < 128){
                float v = 0.f;
                #pragma unroll
                for (int q = 0; q < 8; ++q) v += ld_rmw(&a.par[0*1024 + q*128 + tid]);
                sst[tid] = v;
            }
            __syncthreads();
            const float invN = 1.0f/(8.0f*91.0f);
            float cs[4] = {0,0,0,0}, cq[4] = {0,0,0,0};
            #pragma unroll
            for (int m = 0; m < 4; ++m){
                int c = w + 16*m;
                float ms = sst[2*c], mq = sst[2*c+1];
                float s1 = a.s0a[c], b1 = a.b0a[c];
                for (int t = lane; t < 91; t += 64){
                    float y = bn_gelu(bufs[0][c*BST+t], ms, mq, invN, s1, b1);
                    bufs[0][c*BST+t] = y;
                    cs[m] += y; cq[m] += y*y;
                }
            }
            #pragma unroll
            for (int m = 0; m < 4; ++m){
                #pragma unroll
                for (int off = 32; off > 0; off >>= 1){
                    cs[m] += __shfl_down(cs[m], off, 64);
                    cq[m] += __shfl_down(cq[m], off, 64);
                }
            }
            if (lane == 0){
                #pragma unroll
                for (int m = 0; m < 4; ++m){
                    int c = w + 16*m;
                    red[2*c] = cs[m]; red[2*c+1] = cq[m];
                }
            }
            __syncthreads();
            if (tid < 128) st_rmw(&a.par[1*1024 + wg*128 + tid], red[tid]);
        }
        gsync(a.bar, &phase);
        // ========== 15 residual layers ==========
        int LP = 91;
        for (int i = 0; i < 15; ++i){
            int LQ = LP - 6;
            float* A = bufs[i & 1];
            float* B = bufs[(i + 1) & 1];
            // ---- conv stage: finalize stats(A), transform A in place, conv A->B ----
            {
                int slotP = (i == 0) ? 1 : (3 + 2*(i-1));
                if (tid < 128){
                    float v = 0.f;
                    #pragma unroll
                    for (int q = 0; q < 8; ++q) v += ld_rmw(&a.par[slotP*1024 + q*128 + tid]);
                    sst[tid] = v;
                }
                __syncthreads();
                const float* s2 = (i == 0) ? a.s0b : (a.sb  + 64*(i-1));
                const float* b2 = (i == 0) ? a.b0b : (a.bbv + 64*(i-1));
                const float invNp = 1.0f/(8.0f*(float)LP);
                #pragma unroll
                for (int m = 0; m < 4; ++m){
                    int c = w + 16*m;
                    float ms = sst[2*c], mq = sst[2*c+1];
                    float sv = s2[c], bv = b2[c];
                    for (int t = lane; t < LP; t += 64)
                        A[c*BST+t] = bn_gelu(A[c*BST+t], ms, mq, invNp, sv, bv);
                }
                __syncthreads();
                float acc[8] = {0.f,0.f,0.f,0.f,0.f,0.f,0.f,0.f};
                int t0 = 8*w;
                if (t0 < LQ){
                    const float4* Wt4 = (const float4*)(a.wct + (size_t)i*7*16*256);
                    for (int cihi = 0; cihi < 16; ++cihi){
                        float r[4][16];
                        #pragma unroll
                        for (int cl = 0; cl < 4; ++cl){
                            const float4* ap = (const float4*)&A[(cihi*4+cl)*BST + t0];
                            float4 v0 = ap[0], v1 = ap[1], v2 = ap[2], v3 = ap[3];
                            r[cl][0]=v0.x;  r[cl][1]=v0.y;  r[cl][2]=v0.z;  r[cl][3]=v0.w;
                            r[cl][4]=v1.x;  r[cl][5]=v1.y;  r[cl][6]=v1.z;  r[cl][7]=v1.w;
                            r[cl][8]=v2.x;  r[cl][9]=v2.y;  r[cl][10]=v2.z; r[cl][11]=v2.w;
                            r[cl][12]=v3.x; r[cl][13]=v3.y; r[cl][14]=v3.z; r[cl][15]=v3.w;
                        }
                        #pragma unroll
                        for (int kk = 0; kk < 7; ++kk){
                            float4 wq = Wt4[(kk*16+cihi)*64 + lane];
                            #pragma unroll
                            for (int j = 0; j < 8; ++j){
                                acc[j] = fmaf(r[0][j+kk], wq.x, acc[j]);
                                acc[j] = fmaf(r[1][j+kk], wq.y, acc[j]);
                                acc[j] = fmaf(r[2][j+kk], wq.z, acc[j]);
                                acc[j] = fmaf(r[3][j+kk], wq.w, acc[j]);
                            }
                        }
                    }
                }
                float s = 0.f, sq = 0.f;
                if (t0 < LQ){
                    if (t0 + 8 <= LQ){
                        *(float4*)&B[lane*BST + t0]     = make_float4(acc[0],acc[1],acc[2],acc[3]);
                        *(float4*)&B[lane*BST + t0 + 4] = make_float4(acc[4],acc[5],acc[6],acc[7]);
                        #pragma unroll
                        for (int j = 0; j < 8; ++j){ s += acc[j]; sq += acc[j]*acc[j]; }
                    } else {
                        #pragma unroll
                        for (int j = 0; j < 8; ++j){
                            int t = t0 + j;
                            if (t < LQ){ B[lane*BST + t] = acc[j]; s += acc[j]; sq += acc[j]*acc[j]; }
                        }
                    }
                }
                red[w*128 + 2*lane] = s; red[w*128 + 2*lane + 1] = sq;
                __syncthreads();
                if (tid < 128){
                    float p = 0.f;
                    #pragma unroll
                    for (int q = 0; q < 16; ++q) p += red[q*128 + tid];
                    st_rmw(&a.par[(2+2*i)*1024 + wg*128 + tid], p);
                }
            }
            gsync(a.bar, &phase);
            // ---- elem stage: y = gelu(bn(B)) + A[t+6]*wsk ----
            {
                if (tid < 128){
                    float v = 0.f;
                    #pragma unroll
                    for (int q = 0; q < 8; ++q) v += ld_rmw(&a.par[(2+2*i)*1024 + q*128 + tid]);
                    sst[tid] = v;
                }
                __syncthreads();
                const float* sa_i = a.sa + 64*i;
                const float* ba_i = a.ba + 64*i;
                const float* wsk  = a.wskip + 64*i;
                const float invNq = 1.0f/(8.0f*(float)LQ);
                float cs[4] = {0,0,0,0}, cq[4] = {0,0,0,0};
                #pragma unroll
                for (int m = 0; m < 4; ++m){
                    int c = w + 16*m;
                    float ms = sst[2*c], mq = sst[2*c+1];
                    float s1 = sa_i[c], b1 = ba_i[c], wk = wsk[c];
                    for (int t = lane; t < LQ; t += 64){
                        float y = bn_gelu(B[c*BST+t], ms, mq, invNq, s1, b1) + A[c*BST + t + 6]*wk;
                        B[c*BST+t] = y;
                        cs[m] += y; cq[m] += y*y;
                    }
                }
                #pragma unroll
                for (int m = 0; m < 4; ++m){
                    #pragma unroll
                    for (int off = 32; off > 0; off >>= 1){
                        cs[m] += __shfl_down(cs[m], off, 64);
                        cq[m] += __shfl_down(cq[m], off, 64);
                    }
                }
                if (lane == 0){
                    #pragma unroll
                    for (int m = 0; m < 4; ++m){
                        int c = w + 16*m;
                        red[2*c] = cs[m]; red[2*c+1] = cq[m];
                    }
                }
                __syncthreads();
                if (tid < 128) st_rmw(&a.par[(3+2*i)*1024 + wg*128 + tid], red[tid]);
            }
            gsync(a.bar, &phase);
            LP = LQ;
        }
        // ========== val stage ==========
        {
            float* A = bufs[1];
            if (tid < 128){
                float v = 0.f;
                #pragma unroll
                for (int q = 0; q < 8; ++q) v += ld_rmw(&a.par[31*1024 + q*128 + tid]);
                sst[tid] = v;
            }
            __syncthreads();
            if (w == 0){
                int c = lane;
                float zz = bn_gelu(A[c*BST + 0], sst[2*c], sst[2*c+1], 0.125f,
                                   a.sb[64*14 + c], a.bbv[64*14 + c]) * a.wout[c];
                #pragma unroll
                for (int off = 32; off > 0; off >>= 1) zz += __shfl_down(zz, off, 64);
                if (lane == 0) st_rmw(&a.par[32*1024 + wg], zz);
            }
        }
        gsync(a.bar, &phase);
        // ========== out sample + next window ==========
        {
            if (tid < 8) shv[tid] = ld_rmw(&a.par[32*1024 + tid]);
            __syncthreads();
            if (tid == 0){
                float m = 0.f, q = 0.f;
                #pragma unroll
                for (int b = 0; b < 8; ++b){ m += shv[b]; q += shv[b]*shv[b]; }
                m *= 0.125f;
                float var = q*0.125f - m*m;
                float rs = rsqrtf(var + EPSN);
                float v = (shv[wg] - m)*rs*a.s_out[0] + a.b_out[0];
                a.out[wg*OUTROW + 3968 + k] = v;
                shv[8] = v;
            }
            __syncthreads();
            if (k < NSTEP-1){
                float nv = 0.f;
                if (tid < 194){
                    nv = (tid < 192) ? Wl[tid+2]
                       : ((tid == 192) ? a.x[wg*XROW + L0IN + 2*(k+1)] : shv[8]);
                }
                __syncthreads();
                if (tid < 194) Wl[tid] = nv;
                __syncthreads();
                float s = (tid < 194) ? nv : 0.f;
                float sq = s*s;
                #pragma unroll
                for (int off = 32; off > 0; off >>= 1){
                    s += __shfl_down(s, off, 64);
                    sq += __shfl_down(sq, off, 64);
                }
                if (lane == 0){ red[w] = s; red[16+w] = sq; }
                __syncthreads();
                if (tid == 0){
                    float S = 0.f, Q = 0.f;
                    #pragma unroll
                    for (int q2 = 0; q2 < 16; ++q2){ S += red[q2]; Q += red[16+q2]; }
                    st_rmw(&a.par[33*1024 + wg*2 + 0], S);
                    st_rmw(&a.par[33*1024 + wg*2 + 1], Q);
                }
                gsync(a.bar, &phase);
                if (tid < 2){
                    float v = 0.f;
                    #pragma unroll
                    for (int q2 = 0; q2 < 8; ++q2) v += ld_rmw(&a.par[33*1024 + q2*2 + tid]);
                    stxl[tid] = v;
                }
                __syncthreads();
            }
        }
    }
}

static inline int imin(int a, int b){ return a < b ? a : b; }

extern "C" void kernel_launch(void* const* d_in, const int* in_sizes, int n_in,
                              void* d_out, int out_size, void* d_ws, size_t ws_size,
                              hipStream_t stream){
    const float* x      = (const float*)d_in[0];
    const float* w_in   = (const float*)d_in[1];
    const float* w0     = (const float*)d_in[2];
    const float* w_conv = (const float*)d_in[3];
    const float* w_skip = (const float*)d_in[4];
    const float* w_out  = (const float*)d_in[5];
    const float* s_in   = (const float*)d_in[6];
    const float* b_in   = (const float*)d_in[7];
    const float* s0a    = (const float*)d_in[8];
    const float* b0a    = (const float*)d_in[9];
    const float* s0b    = (const float*)d_in[10];
    const float* b0b    = (const float*)d_in[11];
    const float* sa     = (const float*)d_in[12];
    const float* ba     = (const float*)d_in[13];
    const float* sb     = (const float*)d_in[14];
    const float* bb     = (const float*)d_in[15];
    const float* s_out  = (const float*)d_in[16];
    const float* b_out  = (const float*)d_in[17];
    float* out = (float*)d_out;

    float* ws = (float*)d_ws;
    size_t off = 0;
    float* buf0  = ws + off; off += (size_t)BATCH*L1P1*64;
    float* buf1  = ws + off; off += (size_t)BATCH*L1P1*64;
    float* o_raw = ws + off; off += BATCH*LOUTP1;
    float* W0    = ws + off; off += BATCH*WLEN;
    float* W1    = ws + off; off += BATCH*WLEN;   (void)W1;
    float* stats = ws + off; off += 4200;
    float* STX = stats;
    float* STB = stats + 2;
    int* bar  = (int*)(stats + 4100);

    // phase-2 overlays in buf1 (fully dead after k_convout):
    //   par  [0      .. 34816)   exchange slots (overwrite-before-read)
    //   w0t  [65536  .. 122880)  transposed conv0 weights (written by k_wtrans)
    //   wct  [131072 .. 561152)  transposed conv7 weights
    float* par = buf1;
    float* w0t = buf1 + 65536;
    float* wct = buf1 + 131072;

    hipMemsetAsync((void*)bar, 0, 4*sizeof(int), stream);

    // -------- phase 1 (multi-kernel pipeline, verified) --------
    hipMemsetAsync((void*)STX, 0, 2*sizeof(float), stream);
    k_stats_scalar<<<1, 1024, 0, stream>>>(x, XROW, L0IN, STX);

    {
        int Lin = L0IN;
        int Lc = (Lin - 14)/2 + 1;
        // must cover STB..STOUT inclusive (stats+2 .. stats+4099) — round-3 lesson.
        hipMemsetAsync((void*)STB, 0, 4098*sizeof(float), stream);
        k_conv0<<<dim3((Lc+15)/16, BATCH), 256, 0, stream>>>(x, XROW, Lin, Lc, STX,
                                                             w_in, s_in, b_in, w0, buf0, STB);
        {
            int N = BATCH*Lc*64;
            int g = imin((N+255)/256, 2048);
            k_elem<<<g, 256, 0, stream>>>(buf0, Lc, STB, s0a, b0a,
                                          nullptr, 0, nullptr, nullptr, nullptr, nullptr, stats + 130);
        }
        float* A = buf0; float* Bf = buf1;
        const float* stP = stats + 130; const float* cs2 = s0b; const float* cb2 = b0b;
        int LP = Lc;
        for (int i = 0; i < 15; ++i){
            int LQ = LP - 6;
            float* stY  = stats + 258 + i*256;
            float* stY2 = stY + 128;
            k_conv7<<<dim3((LQ+15)/16, BATCH), 256, 0, stream>>>(A, LP, stP, cs2, cb2,
                                                                 w_conv + (size_t)i*7*64*64, Bf, LQ, stY);
            int N = BATCH*LQ*64;
            int g = imin((N+255)/256, 2048);
            k_elem<<<g, 256, 0, stream>>>(Bf, LQ, stY, sa + 64*i, ba + 64*i,
                                          A, LP, stP, cs2, cb2, w_skip + 64*i, stY2);
            stP = stY2; cs2 = sb + 64*i; cb2 = bb + 64*i;
            float* tmp = A; A = Bf; Bf = tmp;
            LP = LQ;
        }
        int g = imin((BATCH*LP+3)/4, 512);
        k_convout<<<g, 256, 0, stream>>>(A, LP, stP, cs2, cb2, w_out, o_raw, stats + 4098);
    }
    // buf1 is dead after k_convout -> transpose weights into it
    k_wtrans<<<512, 256, 0, stream>>>(w0, w_conv, w0t, wct);
    k_finalize1<<<imin((BATCH*LOUTP1+255)/256, 512), 256, 0, stream>>>(o_raw, stats + 4098, s_out, b_out, out);
    k_initW<<<1, 256, 0, stream>>>(x, out, W0, STX);

    // -------- phase 2: 8-WG LDS-resident persistent kernel --------
    P2A pa;
    pa.x = x; pa.out = out; pa.W = W0; pa.stx = STX;
    pa.par = par; pa.bar = bar;
    pa.w_in = w_in; pa.s_in = s_in; pa.b_in = b_in;
    pa.w0t = w0t; pa.wct = wct; pa.wskip = w_skip; pa.wout = w_out;
    pa.s0a = s0a; pa.b0a = b0a; pa.s0b = s0b; pa.b0b = b0b;
    pa.sa = sa; pa.ba = ba; pa.sb = sb; pa.bbv = bb;
    pa.s_out = s_out; pa.b_out = b_out;

    void* kargs[] = { (void*)&pa };
    hipError_t err = hipLaunchCooperativeKernel((const void*)k_phase2, dim3(G2), dim3(NTH2),
                                                kargs, 0, stream);
    if (err != hipSuccess){
        k_phase2<<<dim3(G2), dim3(NTH2), 0, stream>>>(pa);
    }
}

// Round 11
// 19689.438 us; speedup vs baseline: 1.3642x; 1.3642x over previous
//
#include <hip/hip_runtime.h>
#include <math.h>

#define EPSN 1e-5f
#define BATCH 8
#define NCH 64
#define XROW 8192
#define L0IN 8128
#define L1P1 4058
#define LOUTP1 3968
#define WLEN 194
#define NSTEP 32
#define OUTROW 4000

__device__ __forceinline__ float gelu_f(float x){
    float x3 = x*x*x;
    return 0.5f*x*(1.0f + tanhf(0.7978845608028654f*(x + 0.044715f*x3)));
}

__device__ __forceinline__ float bn_gelu(float v, float sum, float sumsq, float invN, float s, float b){
    float m = sum*invN;
    float var = sumsq*invN - m*m;
    float rs = rsqrtf(var + EPSN);
    return gelu_f((v - m)*rs*s + b);
}

// ---------------- scalar stats (1-channel input), single block ----------------
__global__ void k_stats_scalar(const float* __restrict__ in, int bstride, int T, float* __restrict__ st){
    __shared__ float red[2048];
    int tid = threadIdx.x;
    float s = 0.f, sq = 0.f;
    int N = BATCH*T;
    for (int idx = tid; idx < N; idx += 1024){
        int b = idx / T, t = idx % T;
        float v = in[b*bstride + t];
        s += v; sq += v*v;
    }
    red[tid] = s; red[1024+tid] = sq;
    __syncthreads();
    for (int w = 512; w > 0; w >>= 1){
        if (tid < w){ red[tid] += red[tid+w]; red[1024+tid] += red[1024+tid+w]; }
        __syncthreads();
    }
    if (tid == 0){ st[0] = red[0]; st[1] = red[1024]; }
}

// ---------------- conv k=14 stride=2, 1ch input with analytic layer_in bn+gelu ----------------
__global__ void k_conv0(const float* __restrict__ in, int bstride, int Lin, int Lout,
                        const float* __restrict__ stX,
                        const float* __restrict__ w_in, const float* __restrict__ s_in, const float* __restrict__ b_in,
                        const float* __restrict__ w0,
                        float* __restrict__ out, float* __restrict__ stOut){
    __shared__ float lds[64*45];
    __shared__ float red[512];
    int b = blockIdx.y;
    int t0 = blockIdx.x * 16;
    int tid = threadIdx.x;
    int co = tid & 63, tg = tid >> 6;
    float invNx = 1.0f/(float)(BATCH*Lin);
    float mx = stX[0]*invNx;
    float vx = stX[1]*invNx - mx*mx;
    for (int idx = tid; idx < 44*64; idx += 256){
        int p = idx >> 6; int ci = idx & 63;
        int gp = 2*t0 + p;
        float val = 0.f;
        if (gp < Lin){
            float wc = w_in[ci];
            float raw = in[b*bstride + gp] * wc;
            float var = vx*wc*wc;
            float rs = rsqrtf(var + EPSN);
            val = gelu_f((raw - mx*wc)*rs*s_in[ci] + b_in[ci]);
        }
        lds[ci*45 + p] = val;
    }
    __syncthreads();
    float acc[4] = {0.f,0.f,0.f,0.f};
    for (int ci = 0; ci < 64; ++ci){
        float r[20];
        #pragma unroll
        for (int q = 0; q < 20; ++q) r[q] = lds[ci*45 + 8*tg + q];
        #pragma unroll
        for (int k = 0; k < 14; ++k){
            float w = w0[(k*64+ci)*64 + co];
            #pragma unroll
            for (int j = 0; j < 4; ++j) acc[j] = fmaf(r[2*j+k], w, acc[j]);
        }
    }
    float s = 0.f, sq = 0.f;
    #pragma unroll
    for (int j = 0; j < 4; ++j){
        int t = t0 + tg*4 + j;
        if (t < Lout){
            out[(b*Lout + t)*64 + co] = acc[j];
            s += acc[j]; sq += acc[j]*acc[j];
        }
    }
    red[tid] = s; red[256+tid] = sq;
    __syncthreads();
    if (tg == 0){
        float S  = red[co] + red[co+64] + red[co+128] + red[co+192];
        float SQ = red[256+co] + red[256+co+64] + red[256+co+128] + red[256+co+192];
        atomicAdd(&stOut[2*co],   S);
        atomicAdd(&stOut[2*co+1], SQ);
    }
}

// ---------------- conv k=7 stride=1, input = g(P) applied in LDS stage ----------------
__global__ void k_conv7(const float* __restrict__ P, int LP,
                        const float* __restrict__ stP, const float* __restrict__ s2, const float* __restrict__ b2,
                        const float* __restrict__ w,
                        float* __restrict__ Q, int LQ, float* __restrict__ stQ){
    __shared__ float lds[64*23];
    __shared__ float red[512];
    int b = blockIdx.y;
    int t0 = blockIdx.x * 16;
    int tid = threadIdx.x;
    int co = tid & 63, tg = tid >> 6;
    float invNp = 1.0f/(float)(BATCH*LP);
    for (int idx = tid; idx < 22*64; idx += 256){
        int p = idx >> 6; int ci = idx & 63;
        int gt = t0 + p;
        float val = 0.f;
        if (gt < LP){
            float raw = P[(b*LP + gt)*64 + ci];
            val = bn_gelu(raw, stP[2*ci], stP[2*ci+1], invNp, s2[ci], b2[ci]);
        }
        lds[ci*23 + p] = val;
    }
    __syncthreads();
    float acc[4] = {0.f,0.f,0.f,0.f};
    for (int ci = 0; ci < 64; ++ci){
        float r[10];
        #pragma unroll
        for (int q = 0; q < 10; ++q) r[q] = lds[ci*23 + tg*4 + q];
        #pragma unroll
        for (int k = 0; k < 7; ++k){
            float wv = w[(k*64+ci)*64 + co];
            #pragma unroll
            for (int j = 0; j < 4; ++j) acc[j] = fmaf(r[j+k], wv, acc[j]);
        }
    }
    float s = 0.f, sq = 0.f;
    #pragma unroll
    for (int j = 0; j < 4; ++j){
        int t = t0 + tg*4 + j;
        if (t < LQ){
            Q[(b*LQ + t)*64 + co] = acc[j];
            s += acc[j]; sq += acc[j]*acc[j];
        }
    }
    red[tid] = s; red[256+tid] = sq;
    __syncthreads();
    if (tg == 0){
        float S  = red[co] + red[co+64] + red[co+128] + red[co+192];
        float SQ = red[256+co] + red[256+co+64] + red[256+co+128] + red[256+co+192];
        atomicAdd(&stQ[2*co],   S);
        atomicAdd(&stQ[2*co+1], SQ);
    }
}

// ---------------- elementwise: Q = gelu(bn1(Q_raw)) [+ g(P[t+6])*wsk], stats of result ----------------
__global__ void k_elem(float* __restrict__ Q, int LQ,
                       const float* __restrict__ stQ, const float* __restrict__ s1, const float* __restrict__ b1,
                       const float* __restrict__ P, int LP,
                       const float* __restrict__ stP, const float* __restrict__ s2, const float* __restrict__ b2,
                       const float* __restrict__ wsk,
                       float* __restrict__ stOut){
    __shared__ float red[512];
    int tid = threadIdx.x;
    int c = tid & 63;
    int N = BATCH*LQ*64;
    int stride = gridDim.x*blockDim.x;
    float invNq = 1.0f/(float)(BATCH*LQ);
    float invNp = P ? 1.0f/(float)(BATCH*LP) : 0.f;
    float s = 0.f, sq = 0.f;
    for (int idx = blockIdx.x*blockDim.x + tid; idx < N; idx += stride){
        float v = Q[idx];
        float y = bn_gelu(v, stQ[2*c], stQ[2*c+1], invNq, s1[c], b1[c]);
        if (P){
            int bt = idx >> 6;
            int t  = bt % LQ;
            int bb = bt / LQ;
            float pv = P[(bb*LP + t + 6)*64 + c];
            y += bn_gelu(pv, stP[2*c], stP[2*c+1], invNp, s2[c], b2[c]) * wsk[c];
        }
        Q[idx] = y;
        s += y; sq += y*y;
    }
    red[tid] = s; red[256+tid] = sq;
    __syncthreads();
    if (tid < 64){
        float S  = red[c] + red[c+64] + red[c+128] + red[c+192];
        float SQ = red[256+c] + red[256+c+64] + red[256+c+128] + red[256+c+192];
        atomicAdd(&stOut[2*c],   S);
        atomicAdd(&stOut[2*c+1], SQ);
    }
}

// ---------------- output conv (64->1) with scalar stats ----------------
__global__ void k_convout(const float* __restrict__ P, int LQ,
                          const float* __restrict__ stP, const float* __restrict__ s2, const float* __restrict__ b2,
                          const float* __restrict__ w_out,
                          float* __restrict__ o_raw, float* __restrict__ stOut){
    __shared__ float red[8];
    int tid = threadIdx.x;
    int c = tid & 63, tq = tid >> 6;
    int M = BATCH*LQ;
    float invNp = 1.0f/(float)(BATCH*LQ);
    float myw = w_out[c];
    float ms = stP[2*c], msq = stP[2*c+1], ss = s2[c], bb = b2[c];
    float ls = 0.f, lq = 0.f;
    for (int m = blockIdx.x*4 + tq; m < M; m += gridDim.x*4){
        float pv = P[m*64 + c];
        float val = bn_gelu(pv, ms, msq, invNp, ss, bb) * myw;
        #pragma unroll
        for (int off = 32; off > 0; off >>= 1) val += __shfl_down(val, off, 64);
        if (c == 0){ o_raw[m] = val; ls += val; lq += val*val; }
    }
    if (c == 0){ red[tq] = ls; red[4+tq] = lq; }
    __syncthreads();
    if (tid == 0){
        atomicAdd(&stOut[0], red[0]+red[1]+red[2]+red[3]);
        atomicAdd(&stOut[1], red[4]+red[5]+red[6]+red[7]);
    }
}

// ---------------- phase-1 finalize: z0 -> d_out ----------------
__global__ void k_finalize1(const float* __restrict__ o_raw, const float* __restrict__ st,
                            const float* __restrict__ s_out, const float* __restrict__ b_out,
                            float* __restrict__ out){
    float invN = 1.0f/(float)(BATCH*LOUTP1);
    float m = st[0]*invN;
    float var = st[1]*invN - m*m;
    float rs = rsqrtf(var + EPSN);
    float so = s_out[0], bo = b_out[0];
    int N = BATCH*LOUTP1;
    for (int idx = blockIdx.x*blockDim.x + threadIdx.x; idx < N; idx += gridDim.x*blockDim.x){
        int b = idx / LOUTP1, t = idx % LOUTP1;
        out[b*OUTROW + t] = (o_raw[idx]-m)*rs*so + bo;
    }
}

// ---------------- init rolling window + stats ----------------
__global__ void k_initW(const float* __restrict__ x, const float* __restrict__ out,
                        float* __restrict__ W, float* __restrict__ stX){
    __shared__ float red[512];
    int tid = threadIdx.x;
    float s = 0.f, sq = 0.f;
    for (int idx = tid; idx < BATCH*WLEN; idx += 256){
        int b = idx / WLEN, j = idx % WLEN;
        float v;
        if (j < 192)       v = x[b*XROW + 7936 + j];
        else if (j == 192) v = x[b*XROW + 8128];
        else               v = out[b*OUTROW + 3967];
        W[b*WLEN + j] = v;
        s += v; sq += v*v;
    }
    red[tid] = s; red[256+tid] = sq;
    __syncthreads();
    for (int w = 128; w > 0; w >>= 1){
        if (tid < w){ red[tid] += red[tid+w]; red[256+tid] += red[256+tid+w]; }
        __syncthreads();
    }
    if (tid == 0){ stX[0] = red[0]; stX[1] = red[256]; }
}

// ---------------- weight transpose for phase-2 conv7: [i][k][ci/4][co][ci%4] ----------------
__global__ void k_wtrans(const float* __restrict__ wconv, float* __restrict__ wct){
    int tid = blockIdx.x*256 + threadIdx.x;
    int gs  = gridDim.x*256;
    for (int o = tid; o < 15*7*16*256; o += gs){
        int cilo = o & 3, co = (o>>2)&63, cihi = (o>>8)&15, r = o>>12;
        int kk = r % 7, i = r / 7;
        wct[o] = wconv[((i*7+kk)*64 + cihi*4+cilo)*64 + co];
    }
}

// ================= PHASE 2: 8 WGs (one per b), tensors LDS-resident =================
#define G2 8
#define NTH2 1024
#define BST 100  // float4-aligned; conv reads are wave-uniform broadcasts

// Cross-WG data via atomic RMW at the coherence point (rounds 5-8 lessons).
__device__ __forceinline__ float ld_rmw(float* p){
    return __hip_atomic_fetch_add(p, 0.0f, __ATOMIC_RELAXED, __HIP_MEMORY_SCOPE_AGENT);
}
__device__ __forceinline__ void st_rmw(float* p, float v){
    (void)__hip_atomic_exchange(p, v, __ATOMIC_RELAXED, __HIP_MEMORY_SCOPE_AGENT);
}
__device__ __forceinline__ int ld_rmw_i(int* p){
    return __hip_atomic_fetch_add(p, 0, __ATOMIC_RELAXED, __HIP_MEMORY_SCOPE_AGENT);
}
__device__ __forceinline__ void st_rmw_i(int* p, int v){
    (void)__hip_atomic_exchange(p, v, __ATOMIC_RELAXED, __HIP_MEMORY_SCOPE_AGENT);
}

struct P2A {
    const float* x;
    float* out;
    const float* W;
    const float* stx;
    float* par;        // 34 slots * 1024 floats, overwrite-before-read
    int*   flg;        // SWSR barrier flags: arr[w]@flg[w*16], go[w]@flg[128+w*16]
    const float* w_in; const float* s_in; const float* b_in;
    const float* w0;   // original layout (conv0 scalar path)
    const float* wct;  // 15*7*16*256 transposed (conv7 float4 path)
    const float* wskip; const float* wout;
    const float* s0a; const float* b0a; const float* s0b; const float* b0b;
    const float* sa; const float* ba; const float* sb; const float* bbv;
    const float* s_out; const float* b_out;
};

// Distributed single-writer/single-reader barrier. Round-10 post-mortem: polling one
// shared counter with atomic RMW from 8 WGs forms a coherence-point convoy (each
// poller queues behind 7 others' RMWs). Here every polled cacheline has exactly one
// writer and one reader: WG w>0 arrives on arr[w]; WG0's lanes 1..7 each detect one
// arrival, syncthreads (ALL arrived), then release via per-WG go[w] lines.
__device__ __forceinline__ void gsync(int* flg, int* phase){
    (*phase)++;
    int ph = *phase;
    asm volatile("s_waitcnt vmcnt(0)" ::: "memory");
    __syncthreads();
    int tid = threadIdx.x, wg = blockIdx.x;
    if (wg == 0){
        if (tid >= 1 && tid < 8){
            while (ld_rmw_i(&flg[tid*16]) < ph) __builtin_amdgcn_s_sleep(1);
        }
        __syncthreads();   // all 7 arrivals detected before ANY release
        if (tid >= 1 && tid < 8){
            st_rmw_i(&flg[128 + tid*16], ph);
        }
    } else {
        if (tid == 0){
            st_rmw_i(&flg[wg*16], ph);
            while (ld_rmw_i(&flg[128 + wg*16]) < ph) __builtin_amdgcn_s_sleep(1);
        }
    }
    __syncthreads();
    asm volatile("" ::: "memory");
}

__global__ __launch_bounds__(NTH2, 4) void k_phase2(P2A a){
    __shared__ float g0[64*208];
    __shared__ float bufs[2][64*BST + 16];   // +16 pad: b128 reads may overrun row 63 by <=4
    __shared__ float red[2048];
    __shared__ float sst[128];
    __shared__ float Wl[208];
    __shared__ float shv[16];
    __shared__ float stxl[2];

    const int tid  = threadIdx.x;
    const int wg   = blockIdx.x;
    const int lane = tid & 63;
    const int w    = tid >> 6;
    int phase = 0;

    if (tid < 194)            Wl[tid] = a.W[wg*WLEN + tid];
    else if (tid < 208)       Wl[tid] = 0.f;
    if (tid < 2)              stxl[tid] = a.stx[tid];
    __syncthreads();

    for (int k = 0; k < NSTEP; ++k){
        // ========== stage 0: conv0 (k=14, stride 2) — scalar (verified R8 path) ==========
        {
            const float invNx = 1.0f/(8.0f*194.0f);
            float mx = stxl[0]*invNx;
            float vx = stxl[1]*invNx - mx*mx;
            #pragma unroll
            for (int m = 0; m < 4; ++m){
                int ci = w + 16*m;
                float wc = a.w_in[ci];
                float rs = rsqrtf(vx*wc*wc + EPSN);
                float al = wc*rs*a.s_in[ci];
                float be = a.b_in[ci] - mx*al;
                for (int p = lane; p < 208; p += 64)
                    g0[ci*208 + p] = (p < 194) ? gelu_f(al*Wl[p] + be) : 0.f;
            }
            __syncthreads();
            float acc[8] = {0.f,0.f,0.f,0.f,0.f,0.f,0.f,0.f};
            int t0 = 8*w;
            if (w < 12){
                for (int ci = 0; ci < 64; ++ci){
                    float r[28];
                    #pragma unroll
                    for (int q = 0; q < 28; ++q) r[q] = g0[ci*208 + 2*t0 + q];
                    #pragma unroll
                    for (int kk = 0; kk < 14; ++kk){
                        float wv = a.w0[(kk*64+ci)*64 + lane];
                        #pragma unroll
                        for (int j = 0; j < 8; ++j) acc[j] = fmaf(r[2*j+kk], wv, acc[j]);
                    }
                }
            }
            float s = 0.f, sq = 0.f;
            if (w < 12){
                #pragma unroll
                for (int j = 0; j < 8; ++j){
                    int t = t0 + j;
                    if (t < 91){ bufs[0][lane*BST + t] = acc[j]; s += acc[j]; sq += acc[j]*acc[j]; }
                }
            }
            red[w*128 + 2*lane] = s; red[w*128 + 2*lane + 1] = sq;
            __syncthreads();
            if (tid < 128){
                float p = 0.f;
                #pragma unroll
                for (int q = 0; q < 16; ++q) p += red[q*128 + tid];
                st_rmw(&a.par[0*1024 + wg*128 + tid], p);
            }
        }
        gsync(a.flg, &phase);
        // ========== stage 1: elem0 ==========
        {
            if (tid < 128){
                float v = 0.f;
                #pragma unroll
                for (int q = 0; q < 8; ++q) v += ld_rmw(&a.par[0*1024 + q*128 + tid]);
                sst[tid] = v;
            }
            __syncthreads();
            const float invN = 1.0f/(8.0f*91.0f);
            float cs[4] = {0,0,0,0}, cq[4] = {0,0,0,0};
            #pragma unroll
            for (int m = 0; m < 4; ++m){
                int c = w + 16*m;
                float ms = sst[2*c], mq = sst[2*c+1];
                float s1 = a.s0a[c], b1 = a.b0a[c];
                for (int t = lane; t < 91; t += 64){
                    float y = bn_gelu(bufs[0][c*BST+t], ms, mq, invN, s1, b1);
                    bufs[0][c*BST+t] = y;
                    cs[m] += y; cq[m] += y*y;
                }
            }
            #pragma unroll
            for (int m = 0; m < 4; ++m){
                #pragma unroll
                for (int off = 32; off > 0; off >>= 1){
                    cs[m] += __shfl_down(cs[m], off, 64);
                    cq[m] += __shfl_down(cq[m], off, 64);
                }
            }
            if (lane == 0){
                #pragma unroll
                for (int m = 0; m < 4; ++m){
                    int c = w + 16*m;
                    red[2*c] = cs[m]; red[2*c+1] = cq[m];
                }
            }
            __syncthreads();
            if (tid < 128) st_rmw(&a.par[1*1024 + wg*128 + tid], red[tid]);
        }
        gsync(a.flg, &phase);
        // ========== 15 residual layers ==========
        int LP = 91;
        for (int i = 0; i < 15; ++i){
            int LQ = LP - 6;
            float* A = bufs[i & 1];
            float* B = bufs[(i + 1) & 1];
            // ---- conv stage: finalize stats(A), transform A in place, conv A->B (float4) ----
            {
                int slotP = (i == 0) ? 1 : (3 + 2*(i-1));
                if (tid < 128){
                    float v = 0.f;
                    #pragma unroll
                    for (int q = 0; q < 8; ++q) v += ld_rmw(&a.par[slotP*1024 + q*128 + tid]);
                    sst[tid] = v;
                }
                __syncthreads();
                const float* s2 = (i == 0) ? a.s0b : (a.sb  + 64*(i-1));
                const float* b2 = (i == 0) ? a.b0b : (a.bbv + 64*(i-1));
                const float invNp = 1.0f/(8.0f*(float)LP);
                #pragma unroll
                for (int m = 0; m < 4; ++m){
                    int c = w + 16*m;
                    float ms = sst[2*c], mq = sst[2*c+1];
                    float sv = s2[c], bv = b2[c];
                    for (int t = lane; t < LP; t += 64)
                        A[c*BST+t] = bn_gelu(A[c*BST+t], ms, mq, invNp, sv, bv);
                }
                __syncthreads();
                float acc[8] = {0.f,0.f,0.f,0.f,0.f,0.f,0.f,0.f};
                int t0 = 8*w;
                if (t0 < LQ){
                    const float4* Wt4 = (const float4*)(a.wct + (size_t)i*7*16*256);
                    for (int cihi = 0; cihi < 16; ++cihi){
                        float r[4][16];
                        #pragma unroll
                        for (int cl = 0; cl < 4; ++cl){
                            const float4* ap = (const float4*)&A[(cihi*4+cl)*BST + t0];
                            float4 v0 = ap[0], v1 = ap[1], v2 = ap[2], v3 = ap[3];
                            r[cl][0]=v0.x;  r[cl][1]=v0.y;  r[cl][2]=v0.z;  r[cl][3]=v0.w;
                            r[cl][4]=v1.x;  r[cl][5]=v1.y;  r[cl][6]=v1.z;  r[cl][7]=v1.w;
                            r[cl][8]=v2.x;  r[cl][9]=v2.y;  r[cl][10]=v2.z; r[cl][11]=v2.w;
                            r[cl][12]=v3.x; r[cl][13]=v3.y; r[cl][14]=v3.z; r[cl][15]=v3.w;
                        }
                        #pragma unroll
                        for (int kk = 0; kk < 7; ++kk){
                            float4 wq = Wt4[(kk*16+cihi)*64 + lane];
                            #pragma unroll
                            for (int j = 0; j < 8; ++j){
                                acc[j] = fmaf(r[0][j+kk], wq.x, acc[j]);
                                acc[j] = fmaf(r[1][j+kk], wq.y, acc[j]);
                                acc[j] = fmaf(r[2][j+kk], wq.z, acc[j]);
                                acc[j] = fmaf(r[3][j+kk], wq.w, acc[j]);
                            }
                        }
                    }
                }
                float s = 0.f, sq = 0.f;
                if (t0 < LQ){
                    #pragma unroll
                    for (int j = 0; j < 8; ++j){
                        int t = t0 + j;
                        if (t < LQ){ B[lane*BST + t] = acc[j]; s += acc[j]; sq += acc[j]*acc[j]; }
                    }
                }
                red[w*128 + 2*lane] = s; red[w*128 + 2*lane + 1] = sq;
                __syncthreads();
                if (tid < 128){
                    float p = 0.f;
                    #pragma unroll
                    for (int q = 0; q < 16; ++q) p += red[q*128 + tid];
                    st_rmw(&a.par[(2+2*i)*1024 + wg*128 + tid], p);
                }
            }
            gsync(a.flg, &phase);
            // ---- elem stage: y = gelu(bn(B)) + A[t+6]*wsk ----
            {
                if (tid < 128){
                    float v = 0.f;
                    #pragma unroll
                    for (int q = 0; q < 8; ++q) v += ld_rmw(&a.par[(2+2*i)*1024 + q*128 + tid]);
                    sst[tid] = v;
                }
                __syncthreads();
                const float* sa_i = a.sa + 64*i;
                const float* ba_i = a.ba + 64*i;
                const float* wsk  = a.wskip + 64*i;
                const float invNq = 1.0f/(8.0f*(float)LQ);
                float cs[4] = {0,0,0,0}, cq[4] = {0,0,0,0};
                #pragma unroll
                for (int m = 0; m < 4; ++m){
                    int c = w + 16*m;
                    float ms = sst[2*c], mq = sst[2*c+1];
                    float s1 = sa_i[c], b1 = ba_i[c], wk = wsk[c];
                    for (int t = lane; t < LQ; t += 64){
                        float y = bn_gelu(B[c*BST+t], ms, mq, invNq, s1, b1) + A[c*BST + t + 6]*wk;
                        B[c*BST+t] = y;
                        cs[m] += y; cq[m] += y*y;
                    }
                }
                #pragma unroll
                for (int m = 0; m < 4; ++m){
                    #pragma unroll
                    for (int off = 32; off > 0; off >>= 1){
                        cs[m] += __shfl_down(cs[m], off, 64);
                        cq[m] += __shfl_down(cq[m], off, 64);
                    }
                }
                if (lane == 0){
                    #pragma unroll
                    for (int m = 0; m < 4; ++m){
                        int c = w + 16*m;
                        red[2*c] = cs[m]; red[2*c+1] = cq[m];
                    }
                }
                __syncthreads();
                if (tid < 128) st_rmw(&a.par[(3+2*i)*1024 + wg*128 + tid], red[tid]);
            }
            gsync(a.flg, &phase);
            LP = LQ;
        }
        // ========== val stage ==========
        {
            float* A = bufs[1];
            if (tid < 128){
                float v = 0.f;
                #pragma unroll
                for (int q = 0; q < 8; ++q) v += ld_rmw(&a.par[31*1024 + q*128 + tid]);
                sst[tid] = v;
            }
            __syncthreads();
            if (w == 0){
                int c = lane;
                float zz = bn_gelu(A[c*BST + 0], sst[2*c], sst[2*c+1], 0.125f,
                                   a.sb[64*14 + c], a.bbv[64*14 + c]) * a.wout[c];
                #pragma unroll
                for (int off = 32; off > 0; off >>= 1) zz += __shfl_down(zz, off, 64);
                if (lane == 0) st_rmw(&a.par[32*1024 + wg], zz);
            }
        }
        gsync(a.flg, &phase);
        // ========== out sample + next window ==========
        {
            if (tid < 8) shv[tid] = ld_rmw(&a.par[32*1024 + tid]);
            __syncthreads();
            if (tid == 0){
                float m = 0.f, q = 0.f;
                #pragma unroll
                for (int b = 0; b < 8; ++b){ m += shv[b]; q += shv[b]*shv[b]; }
                m *= 0.125f;
                float var = q*0.125f - m*m;
                float rs = rsqrtf(var + EPSN);
                float v = (shv[wg] - m)*rs*a.s_out[0] + a.b_out[0];
                a.out[wg*OUTROW + 3968 + k] = v;
                shv[8] = v;
            }
            __syncthreads();
            if (k < NSTEP-1){
                float nv = 0.f;
                if (tid < 194){
                    nv = (tid < 192) ? Wl[tid+2]
                       : ((tid == 192) ? a.x[wg*XROW + L0IN + 2*(k+1)] : shv[8]);
                }
                __syncthreads();
                if (tid < 194) Wl[tid] = nv;
                __syncthreads();
                float s = (tid < 194) ? nv : 0.f;
                float sq = s*s;
                #pragma unroll
                for (int off = 32; off > 0; off >>= 1){
                    s += __shfl_down(s, off, 64);
                    sq += __shfl_down(sq, off, 64);
                }
                if (lane == 0){ red[w] = s; red[16+w] = sq; }
                __syncthreads();
                if (tid == 0){
                    float S = 0.f, Q = 0.f;
                    #pragma unroll
                    for (int q2 = 0; q2 < 16; ++q2){ S += red[q2]; Q += red[16+q2]; }
                    st_rmw(&a.par[33*1024 + wg*2 + 0], S);
                    st_rmw(&a.par[33*1024 + wg*2 + 1], Q);
                }
                gsync(a.flg, &phase);
                if (tid < 2){
                    float v = 0.f;
                    #pragma unroll
                    for (int q2 = 0; q2 < 8; ++q2) v += ld_rmw(&a.par[33*1024 + q2*2 + tid]);
                    stxl[tid] = v;
                }
                __syncthreads();
            }
        }
    }
}

static inline int imin(int a, int b){ return a < b ? a : b; }

extern "C" void kernel_launch(void* const* d_in, const int* in_sizes, int n_in,
                              void* d_out, int out_size, void* d_ws, size_t ws_size,
                              hipStream_t stream){
    const float* x      = (const float*)d_in[0];
    const float* w_in   = (const float*)d_in[1];
    const float* w0     = (const float*)d_in[2];
    const float* w_conv = (const float*)d_in[3];
    const float* w_skip = (const float*)d_in[4];
    const float* w_out  = (const float*)d_in[5];
    const float* s_in   = (const float*)d_in[6];
    const float* b_in   = (const float*)d_in[7];
    const float* s0a    = (const float*)d_in[8];
    const float* b0a    = (const float*)d_in[9];
    const float* s0b    = (const float*)d_in[10];
    const float* b0b    = (const float*)d_in[11];
    const float* sa     = (const float*)d_in[12];
    const float* ba     = (const float*)d_in[13];
    const float* sb     = (const float*)d_in[14];
    const float* bb     = (const float*)d_in[15];
    const float* s_out  = (const float*)d_in[16];
    const float* b_out  = (const float*)d_in[17];
    float* out = (float*)d_out;

    float* ws = (float*)d_ws;
    size_t off = 0;
    float* buf0  = ws + off; off += (size_t)BATCH*L1P1*64;
    float* buf1  = ws + off; off += (size_t)BATCH*L1P1*64;
    float* o_raw = ws + off; off += BATCH*LOUTP1;
    float* W0    = ws + off; off += BATCH*WLEN;
    float* W1    = ws + off; off += BATCH*WLEN;   (void)W1;
    float* stats = ws + off; off += 4200;
    float* STX = stats;
    float* STB = stats + 2;

    // phase-2 overlays in buf1 (fully dead after k_convout):
    //   par   [0     .. 34816)  exchange slots (overwrite-before-read)
    //   flags [40960 .. 41216)  SWSR barrier flags (256 ints, memset per call)
    //   wct   [65536 .. 495616) transposed conv7 weights
    float* par = buf1;
    int*   flg = (int*)(buf1 + 40960);
    float* wct = buf1 + 65536;

    // -------- phase 1 (multi-kernel pipeline, verified) --------
    hipMemsetAsync((void*)STX, 0, 2*sizeof(float), stream);
    k_stats_scalar<<<1, 1024, 0, stream>>>(x, XROW, L0IN, STX);

    {
        int Lin = L0IN;
        int Lc = (Lin - 14)/2 + 1;
        // must cover STB..STOUT inclusive (stats+2 .. stats+4099) — round-3 lesson.
        hipMemsetAsync((void*)STB, 0, 4098*sizeof(float), stream);
        k_conv0<<<dim3((Lc+15)/16, BATCH), 256, 0, stream>>>(x, XROW, Lin, Lc, STX,
                                                             w_in, s_in, b_in, w0, buf0, STB);
        {
            int N = BATCH*Lc*64;
            int g = imin((N+255)/256, 2048);
            k_elem<<<g, 256, 0, stream>>>(buf0, Lc, STB, s0a, b0a,
                                          nullptr, 0, nullptr, nullptr, nullptr, nullptr, stats + 130);
        }
        float* A = buf0; float* Bf = buf1;
        const float* stP = stats + 130; const float* cs2 = s0b; const float* cb2 = b0b;
        int LP = Lc;
        for (int i = 0; i < 15; ++i){
            int LQ = LP - 6;
            float* stY  = stats + 258 + i*256;
            float* stY2 = stY + 128;
            k_conv7<<<dim3((LQ+15)/16, BATCH), 256, 0, stream>>>(A, LP, stP, cs2, cb2,
                                                                 w_conv + (size_t)i*7*64*64, Bf, LQ, stY);
            int N = BATCH*LQ*64;
            int g = imin((N+255)/256, 2048);
            k_elem<<<g, 256, 0, stream>>>(Bf, LQ, stY, sa + 64*i, ba + 64*i,
                                          A, LP, stP, cs2, cb2, w_skip + 64*i, stY2);
            stP = stY2; cs2 = sb + 64*i; cb2 = bb + 64*i;
            float* tmp = A; A = Bf; Bf = tmp;
            LP = LQ;
        }
        int g = imin((BATCH*LP+3)/4, 512);
        k_convout<<<g, 256, 0, stream>>>(A, LP, stP, cs2, cb2, w_out, o_raw, stats + 4098);
    }
    // buf1 dead after k_convout -> zero barrier flags, transpose weights into it
    hipMemsetAsync((void*)flg, 0, 256*sizeof(int), stream);
    k_wtrans<<<512, 256, 0, stream>>>(w_conv, wct);
    k_finalize1<<<imin((BATCH*LOUTP1+255)/256, 512), 256, 0, stream>>>(o_raw, stats + 4098, s_out, b_out, out);
    k_initW<<<1, 256, 0, stream>>>(x, out, W0, STX);

    // -------- phase 2: 8-WG LDS-resident persistent kernel --------
    P2A pa;
    pa.x = x; pa.out = out; pa.W = W0; pa.stx = STX;
    pa.par = par; pa.flg = flg;
    pa.w_in = w_in; pa.s_in = s_in; pa.b_in = b_in;
    pa.w0 = w0; pa.wct = wct; pa.wskip = w_skip; pa.wout = w_out;
    pa.s0a = s0a; pa.b0a = b0a; pa.s0b = s0b; pa.b0b = b0b;
    pa.sa = sa; pa.ba = ba; pa.sb = sb; pa.bbv = bb;
    pa.s_out = s_out; pa.b_out = b_out;

    void* kargs[] = { (void*)&pa };
    hipError_t err = hipLaunchCooperativeKernel((const void*)k_phase2, dim3(G2), dim3(NTH2),
                                                kargs, 0, stream);
    if (err != hipSuccess){
        k_phase2<<<dim3(G2), dim3(NTH2), 0, stream>>>(pa);
    }
}